// Round 12
// baseline (164.013 us; speedup 1.0000x reference)
//
#include <hip/hip_runtime.h>
#include <hip/hip_bf16.h>

// Problem constants
#define B_ 2
#define S_ 1024
#define I_ 512
#define C_ 32
#define EPS_ 1e-5f

// ---------------------------------------------------------------------------
// a_t/b_t layout (v11, unchanged): [b][sg][ig][i_l][c][s64]
//   s64: 64 elems contiguous; c: stride 64 -> wave block 4 KB contiguous
//   i_l: ILST=2064 (non-pow2), ig: 4*ILST, sg: 128*IGST, b: 16*SGST
// ---------------------------------------------------------------------------
#define ILST 2064
#define IGST (4 * ILST)            // 8256 elems
#define SGST (128 * IGST)          // 1,056,768 elems
#define BST  (16 * SGST)           // 16,908,288 elems

// GEMM tiling: 256x256 tile, 8 waves, BK=32, double-buffered.
#define GBM 256
#define GBN 256
#define BK 32
#define NT (S_ / BK)   // 32 K-steps

typedef __attribute__((ext_vector_type(8))) short bf16x8;   // 8 bf16 = 4 VGPRs (MFMA A/B frag)
typedef __attribute__((ext_vector_type(4))) short bf16x4;   // 4 bf16 = 8 B
typedef __attribute__((ext_vector_type(4))) float f32x4;    // MFMA C/D frag

static __device__ __forceinline__ short f2bf(float f) {
    union { __hip_bfloat16 h; short s; } u;
    u.h = __float2bfloat16(f);
    return u.s;
}

// ---------------------------------------------------------------------------
// Pass 0 (v12): BARRIER-FREE wave-independent LN + MFMA projection.
//
// Round-11 post-mortem: 7 variants pinned at 80-93us; volumes exact, rate
// 2.5 TB/s vs 6.7 achievable. The invariant never removed: __syncthreads
// lockstep (all waves load together, store together -> memory pipe sees
// alternating pure-read/pure-write phases + full per-block latency chain).
//
// v12: wave w owns (i = i0+w, s = s0+lane) -> its 64 rows are EXACTLY the
// 4 MFMA A-frags. mhf is wave-private (4KB slice, XOR swizzle), ds_write ->
// ds_read is same-wave (HW in-order DS) -> BOTH barriers deleted. Transpose
// buf overlays the wave's own mhf slice after frag reads. LDS 18 KiB -> 8
// blocks/CU. Waves drift freely -> continuous R/W interleave. Global stores
// are nontemporal (keep m L3-resident; a_t/b_t are streamed to pass 1).
// ---------------------------------------------------------------------------
__global__ __launch_bounds__(256) void ln_proj_kernel(
    const float* __restrict__ m,
    const float* __restrict__ g, const float* __restrict__ beta,
    const float* __restrict__ Wa, const float* __restrict__ ba,
    const float* __restrict__ Wb, const float* __restrict__ bb,
    __hip_bfloat16* __restrict__ a_t, __hip_bfloat16* __restrict__ b_t)
{
    __shared__ __align__(16) char ldsraw[4 * 4608];   // 18 KiB: per-wave 4608 B
    // per-wave slice: first used as frag-linear mh (4096 B), then reused as
    // transpose buffer (4590 B) after the A-frag reads (same-wave, no barrier).

    const int tid  = threadIdx.x;
    const int lane = tid & 63;
    const int w    = tid >> 6;
    const int lo   = lane & 15;
    const int hi   = lane >> 4;

    const int blk = blockIdx.x;                 // ((b*16 + sg)*128 + ig), ig fastest
    const int ig = blk & 127;
    const int sg = (blk >> 7) & 15;
    const int b  = blk >> 11;
    const int s0 = sg * 64;
    const int i  = ig * 4 + w;                  // wave-owned output row

    // ---- issue own-row loads FIRST (lane <-> s; 8 independent float4) ----
    const float* mp = m + ((size_t)(b * S_ + s0 + lane) * I_ + i) * C_;
    float4 mv[8];
#pragma unroll
    for (int v = 0; v < 8; ++v) mv[v] = reinterpret_cast<const float4*>(mp)[v];

    // ---- B-frags: Wa/Wb rows as bf16x8 (latency hidden under m-loads) ----
    bf16x8 bw[4];
    float biasv[4];
#pragma unroll
    for (int f = 0; f < 4; ++f) {
        const float* Wsrc = (f & 2) ? Wb : Wa;
        const float* bsrc = (f & 2) ? bb : ba;
        int c = (f & 1) * 16 + lo;
        const float* src = Wsrc + c * C_ + hi * 8;
        float4 u0 = *reinterpret_cast<const float4*>(src);
        float4 u1 = *reinterpret_cast<const float4*>(src + 4);
        bf16x8 ch;
        ch[0] = f2bf(u0.x); ch[1] = f2bf(u0.y); ch[2] = f2bf(u0.z); ch[3] = f2bf(u0.w);
        ch[4] = f2bf(u1.x); ch[5] = f2bf(u1.y); ch[6] = f2bf(u1.z); ch[7] = f2bf(u1.w);
        bw[f] = ch;
        biasv[f] = bsrc[c];
    }

    // ---- LN, pure register math ----
    float x[C_];
#pragma unroll
    for (int v = 0; v < 8; ++v) {
        x[4*v+0] = mv[v].x; x[4*v+1] = mv[v].y; x[4*v+2] = mv[v].z; x[4*v+3] = mv[v].w;
    }
    float mu = 0.f;
#pragma unroll
    for (int c = 0; c < C_; ++c) mu += x[c];
    mu *= (1.f / C_);
    float var = 0.f;
#pragma unroll
    for (int c = 0; c < C_; ++c) { float dd = x[c] - mu; var += dd * dd; }
    float rs = rsqrtf(var * (1.f / C_) + EPS_);
#pragma unroll
    for (int c = 0; c < C_; ++c) x[c] = (x[c] - mu) * rs * g[c] + beta[c];

    // ---- pack + wave-private frag-linear LDS write (XOR swizzle by q) ----
    // position p = lane (s index within the wave's 64-s window); frag q = hi.
    char* wlds = ldsraw + w * 4608;
    {
        const int swz = hi << 5;                // region q into bank bits 5-6
#pragma unroll
        for (int ks = 0; ks < 4; ++ks) {
            bf16x8 ch;
#pragma unroll
            for (int e = 0; e < 8; ++e) ch[e] = f2bf(x[ks * 8 + e]);
            int byte = hi * 1024 + ((ks * 256 + lo * 16) ^ swz);
            *reinterpret_cast<bf16x8*>(wlds + byte) = ch;
        }
    }

    // ---- A-frag reads (same wave -> HW in-order DS, no barrier) ----
    bf16x8 af[4];
#pragma unroll
    for (int q = 0; q < 4; ++q) {
        int byte = q * 1024 + ((lane * 16) ^ (q << 5));
        af[q] = *reinterpret_cast<const bf16x8*>(wlds + byte);
    }

    // ---- p-loop: 2 MFMAs live at a time; transpose via overlay of own slice ----
    __hip_bfloat16* trw = reinterpret_cast<__hip_bfloat16*>(wlds);  // overlays mh (af in regs)
    const size_t wbase = (size_t)b * BST + (size_t)sg * SGST
                       + (size_t)ig * IGST + (size_t)w * ILST;
#pragma unroll
    for (int p = 0; p < 2; ++p) {
#pragma unroll
        for (int q = 0; q < 4; ++q) {
#pragma unroll
            for (int fh = 0; fh < 2; ++fh) {
                int f = p * 2 + fh;
                f32x4 d = __builtin_amdgcn_mfma_f32_16x16x32_bf16(
                    af[q], bw[f], (f32x4){0.f, 0.f, 0.f, 0.f}, 0, 0, 0);
                bf16x4 v4;
#pragma unroll
                for (int r = 0; r < 4; ++r) v4[r] = f2bf(d[r] + biasv[f]);
                int c = fh * 16 + lo;
                int s = q * 16 + hi * 4;
                *reinterpret_cast<bf16x4*>(trw + c * 72 + s) = v4;
            }
        }
        __hip_bfloat16* outp = p ? b_t : a_t;
#pragma unroll
        for (int cg = 0; cg < 4; ++cg) {
            int c  = cg * 8 + (lane >> 3);
            int s8 = (lane & 7) * 8;
            bf16x8 vv = *reinterpret_cast<const bf16x8*>(trw + c * 72 + s8);
            // contiguous 1 KiB per wave-store; nontemporal: don't pollute L2/L3
            __builtin_nontemporal_store(
                vv, reinterpret_cast<bf16x8*>(outp + wbase + cg * 512 + lane * 8));
        }
    }
}

// ---------------------------------------------------------------------------
// Pass 1 (unchanged v11): 64 independent GEMMs, 256x256 tiles, 8 waves,
// BK=32 dbuf via global_load_lds w=16, read-side XOR swizzle with source
// pre-swizzle (rule 21), T1 XCD swizzle, bf16 epilogue with 1/S folded.
// ---------------------------------------------------------------------------
__global__ __launch_bounds__(512, 2) void opm_gemm_kernel(
    const __hip_bfloat16* __restrict__ a_t,
    const __hip_bfloat16* __restrict__ b_t,
    __hip_bfloat16* __restrict__ outer)
{
    __shared__ __align__(16) __hip_bfloat16 sA[2][GBM * BK];  // 16 KiB per buf
    __shared__ __align__(16) __hip_bfloat16 sB[2][GBN * BK];  // total 64 KiB

    const int tid  = threadIdx.x;
    const int wave = tid >> 6;           // 0..7
    const int lane = tid & 63;
    // T1: 256 blocks % 8 == 0 -> bijective chunked swizzle (32 blocks/XCD)
    const int swz  = (blockIdx.x & 7) * 32 + (blockIdx.x >> 3);
    const int bc   = swz >> 2;           // (b*C + c), 0..63
    const int tile = swz & 3;            // 2x2 output tiles per GEMM
    const int i0   = (tile >> 1) * GBM;
    const int j0   = (tile & 1)  * GBN;

    const char* Ap = (const char*)a_t + ((size_t)(bc >> 5) * BST + (size_t)(bc & 31) * 64
                                        + (size_t)(i0 >> 2) * IGST) * 2;
    const char* Bp = (const char*)b_t + ((size_t)(bc >> 5) * BST + (size_t)(bc & 31) * 64
                                        + (size_t)(j0 >> 2) * IGST) * 2;

    f32x4 acc[8][4];
#pragma unroll
    for (int mI = 0; mI < 8; ++mI)
#pragma unroll
        for (int nI = 0; nI < 4; ++nI)
            acc[mI][nI] = (f32x4){0.f, 0.f, 0.f, 0.f};

    const int wr = wave >> 2;      // wave row (0..1): rows [wr*128, +128)
    const int wc = wave & 3;       // wave col (0..3): cols [wc*64, +64)
    const int half = lane >> 4;    // k-group
    const int lrow = lane & 15;

    // staging: thread -> (row = tid>>2, piece = tid&3); source piece
    // pre-swizzled by (row>>1)&3 so the read-side XOR lands linear (rule 21).
    const int row_me = tid >> 2;                       // 0..127
    const int kb_me  = (((tid & 3) ^ ((tid >> 3) & 3)) << 4);
    const size_t rowoff = ((size_t)(row_me >> 2) * IGST + (size_t)(row_me & 3) * ILST) * 2;
    const size_t ROW128 = (size_t)32 * IGST * 2;       // +128 rows in bytes

#define STAGE(bufidx, t) do {                                                              \
        const size_t sgo = (size_t)((t) >> 1) * (SGST * 2);                                \
        const int    sho = ((t) & 1) * 64;                                                 \
        const char* gA0 = Ap + sgo + rowoff + sho + kb_me;                                 \
        const char* gB0 = Bp + sgo + rowoff + sho + kb_me;                                 \
        char* lA = (char*)(&sA[bufidx][0]) + tid * 16;                                     \
        char* lB = (char*)(&sB[bufidx][0]) + tid * 16;                                     \
        __builtin_amdgcn_global_load_lds((const __attribute__((address_space(1))) void*)gA0,              \
                                         (__attribute__((address_space(3))) void*)lA, 16, 0, 0);          \
        __builtin_amdgcn_global_load_lds((const __attribute__((address_space(1))) void*)(gA0 + ROW128),   \
                                         (__attribute__((address_space(3))) void*)(lA + 8192), 16, 0, 0); \
        __builtin_amdgcn_global_load_lds((const __attribute__((address_space(1))) void*)gB0,              \
                                         (__attribute__((address_space(3))) void*)lB, 16, 0, 0);          \
        __builtin_amdgcn_global_load_lds((const __attribute__((address_space(1))) void*)(gB0 + ROW128),   \
                                         (__attribute__((address_space(3))) void*)(lB + 8192), 16, 0, 0); \
    } while (0)

    STAGE(0, 0);
    asm volatile("s_waitcnt vmcnt(0)" ::: "memory");
    __syncthreads();

#pragma unroll 2
    for (int t = 0; t < NT; ++t) {
        const int cur = t & 1;
        if (t + 1 < NT) STAGE(cur ^ 1, t + 1);   // prefetch next K-slab

        const char* lA = (const char*)(&sA[cur][0]);
        const char* lB = (const char*)(&sB[cur][0]);
        bf16x8 af[8], bfr[4];
#pragma unroll
        for (int mI = 0; mI < 8; ++mI) {
            int row  = wr * 128 + mI * 16 + lrow;
            int byte = (row * 64 + half * 16) ^ (((row >> 1) & 3) << 4);
            af[mI] = *reinterpret_cast<const bf16x8*>(lA + byte);
        }
#pragma unroll
        for (int nI = 0; nI < 4; ++nI) {
            int row  = wc * 64 + nI * 16 + lrow;
            int byte = (row * 64 + half * 16) ^ (((row >> 1) & 3) << 4);
            bfr[nI] = *reinterpret_cast<const bf16x8*>(lB + byte);
        }
#pragma unroll
        for (int mI = 0; mI < 8; ++mI)
#pragma unroll
            for (int nI = 0; nI < 4; ++nI)
                acc[mI][nI] = __builtin_amdgcn_mfma_f32_16x16x32_bf16(af[mI], bfr[nI], acc[mI][nI], 0, 0, 0);

        __syncthreads();   // drains vmcnt+lgkmcnt (buffers safe to swap)
    }
#undef STAGE

    // C/D layout: col = lane&15 (from B), row = (lane>>4)*4 + reg (from A)
    __hip_bfloat16* Op = outer + (size_t)bc * (I_ * I_);
#pragma unroll
    for (int mI = 0; mI < 8; ++mI) {
        int ii = i0 + wr * 128 + mI * 16 + half * 4;
#pragma unroll
        for (int nI = 0; nI < 4; ++nI) {
            int jj = j0 + wc * 64 + nI * 16 + lrow;
#pragma unroll
            for (int r = 0; r < 4; ++r)
                Op[(size_t)(ii + r) * I_ + jj] =
                    __float2bfloat16(acc[mI][nI][r] * (1.f / S_));
        }
    }
}

// ---------------------------------------------------------------------------
// Pass 2: out[b,i,j,c] = bo[c] + sum_c' Wo[c,c'] * outer_scaled[(b,c'),i,j]
// ---------------------------------------------------------------------------
__global__ __launch_bounds__(256) void wo_kernel(
    const __hip_bfloat16* __restrict__ outer,
    const float* __restrict__ Wo, const float* __restrict__ bo,
    float* __restrict__ out)
{
    int tid = blockIdx.x * 256 + threadIdx.x;   // ((b*I + i)*J + j)
    int j  = tid & (I_ - 1);
    int bi = tid >> 9;
    int i  = bi & (I_ - 1);
    int b  = bi >> 9;

    const __hip_bfloat16* ip = outer + ((size_t)(b * C_) * I_ + i) * I_ + j;
    float v[C_];
#pragma unroll
    for (int c = 0; c < C_; ++c) v[c] = __bfloat162float(ip[(size_t)c * (I_ * I_)]);

    float o[C_];
#pragma unroll
    for (int c = 0; c < C_; ++c) {
        float acc = bo[c];
#pragma unroll
        for (int k = 0; k < C_; ++k) acc = fmaf(Wo[c * C_ + k], v[k], acc);
        o[c] = acc;
    }

    float* op = out + (size_t)tid * C_;
#pragma unroll
    for (int vv = 0; vv < 8; ++vv) {
        float4 t4 = { o[4*vv+0], o[4*vv+1], o[4*vv+2], o[4*vv+3] };
        reinterpret_cast<float4*>(op)[vv] = t4;
    }
}

// ---------------------------------------------------------------------------
extern "C" void kernel_launch(void* const* d_in, const int* in_sizes, int n_in,
                              void* d_out, int out_size, void* d_ws, size_t ws_size,
                              hipStream_t stream) {
    const float* m    = (const float*)d_in[0];
    const float* ln_g = (const float*)d_in[1];
    const float* ln_b = (const float*)d_in[2];
    const float* Wa   = (const float*)d_in[3];
    const float* ba   = (const float*)d_in[4];
    const float* Wb   = (const float*)d_in[5];
    const float* bb   = (const float*)d_in[6];
    const float* Wo   = (const float*)d_in[7];
    const float* bo   = (const float*)d_in[8];
    float* out = (float*)d_out;

    const size_t AEL = (size_t)B_ * BST;            // elems per array (padded)
    const size_t nO  = (size_t)B_ * C_ * I_ * I_;   // 16,777,216 elems (32 MiB bf16)
    const size_t need = (AEL * 2 + nO) * sizeof(__hip_bfloat16);  // ~169 MB
    if (ws_size < need) return;   // diagnostic: output stays zero -> ws too small

    __hip_bfloat16* a_t = (__hip_bfloat16*)d_ws;
    __hip_bfloat16* b_t = a_t + AEL;
    __hip_bfloat16* outer = b_t + AEL;

    ln_proj_kernel<<<B_ * 16 * 128, 256, 0, stream>>>(m, ln_g, ln_b, Wa, ba, Wb, bb, a_t, b_t);
    opm_gemm_kernel<<<B_ * C_ * 4, 512, 0, stream>>>(a_t, b_t, outer);
    wo_kernel<<<(B_ * I_ * I_) / 256, 256, 0, stream>>>(outer, Wo, bo, out);
}

// Round 13
// 141.046 us; speedup vs baseline: 1.1628x; 1.1628x over previous
//
#include <hip/hip_runtime.h>
#include <hip/hip_bf16.h>

// Problem constants
#define B_ 2
#define S_ 1024
#define I_ 512
#define C_ 32
#define EPS_ 1e-5f

// ---------------------------------------------------------------------------
// a_t/b_t layout (v11, unchanged): [b][sg][ig][i_l][c][s64]
//   s64: 64 elems contiguous; c: stride 64 -> wave block 4 KB contiguous
//   i_l: ILST=2064 (non-pow2), ig: 4*ILST, sg: 128*IGST, b: 16*SGST
// ---------------------------------------------------------------------------
#define ILST 2064
#define IGST (4 * ILST)            // 8256 elems
#define SGST (128 * IGST)          // 1,056,768 elems
#define BST  (16 * SGST)           // 16,908,288 elems

// GEMM tiling: 256x256 tile, 8 waves, BK=32, double-buffered.
#define GBM 256
#define GBN 256
#define BK 32
#define NT (S_ / BK)   // 32 K-steps

typedef __attribute__((ext_vector_type(8))) short bf16x8;   // 8 bf16 = 4 VGPRs (MFMA A/B frag)
typedef __attribute__((ext_vector_type(4))) short bf16x4;   // 4 bf16 = 8 B
typedef __attribute__((ext_vector_type(4))) float f32x4;    // MFMA C/D frag

static __device__ __forceinline__ short f2bf(float f) {
    union { __hip_bfloat16 h; short s; } u;
    u.h = __float2bfloat16(f);
    return u.s;
}

// ---------------------------------------------------------------------------
// Pass 0 (v13): COALESCED staged reads + v11 fast compute path.
//
// Round-12 post-mortem: occupancy 23/32/33/60% all ~85us -> occupancy,
// barriers, write granule all exonerated. The never-changed invariant:
// scattered reads (each wave-load = 64 distinct lines at 64KB strides;
// ~27us/CU of TA line-request serialization + poor DRAM sector locality).
//
// v13: stage the 32KB m-slab with DENSE loads (per s-chunk 512B contiguous;
// per wave-instr 2x512B = 16 lines) into xs with stride-33 fp32 rows,
// r = s*4+i (stage-write ~2-way, row-read ~2-way banks = free). Thread tid
// reads row r=tid, LN in regs, then v11 path: frag-linear swizzled mhf,
// per-wave A-frags, acc-diet MFMA, transpose (overlays dead xs), 1-KiB
// contiguous wave-stores. 2 barriers, ~50KB LDS.
// ---------------------------------------------------------------------------
__global__ __launch_bounds__(256) void ln_proj_kernel(
    const float* __restrict__ m,
    const float* __restrict__ g, const float* __restrict__ beta,
    const float* __restrict__ Wa, const float* __restrict__ ba,
    const float* __restrict__ Wb, const float* __restrict__ bb,
    __hip_bfloat16* __restrict__ a_t, __hip_bfloat16* __restrict__ b_t)
{
    __shared__ __align__(16) float xs[256 * 33 + 4];        // 33.8 KiB staging
    __shared__ __align__(16) __hip_bfloat16 mhf[8192];      // 16 KiB frag-linear mh

    const int tid  = threadIdx.x;
    const int lane = tid & 63;
    const int w    = tid >> 6;
    const int lo   = lane & 15;
    const int hi   = lane >> 4;

    const int blk = blockIdx.x;                 // ((b*16 + sg)*128 + ig), ig fastest
    const int ig = blk & 127;
    const int sg = (blk >> 7) & 15;
    const int b  = blk >> 11;
    const int s0 = sg * 64;
    const int i0 = ig * 4;

    // thread <-> row: i_l = tid&3, s_l = tid>>2  (row index r = s_l*4+i_l = tid)
    const int i_l = tid & 3;
    const int s_l = tid >> 2;

    // ---- B-frags: Wa/Wb rows as bf16x8 (lane l: W[c=(f&1)*16+lo][k=hi*8+e]) ----
    bf16x8 bw[4];
    float biasv[4];
#pragma unroll
    for (int f = 0; f < 4; ++f) {
        const float* Wsrc = (f & 2) ? Wb : Wa;
        const float* bsrc = (f & 2) ? bb : ba;
        int c = (f & 1) * 16 + lo;
        const float* src = Wsrc + c * C_ + hi * 8;
        float4 u0 = *reinterpret_cast<const float4*>(src);
        float4 u1 = *reinterpret_cast<const float4*>(src + 4);
        bf16x8 ch;
        ch[0] = f2bf(u0.x); ch[1] = f2bf(u0.y); ch[2] = f2bf(u0.z); ch[3] = f2bf(u0.w);
        ch[4] = f2bf(u1.x); ch[5] = f2bf(u1.y); ch[6] = f2bf(u1.z); ch[7] = f2bf(u1.w);
        bw[f] = ch;
        biasv[f] = bsrc[c];
    }

    // ---- Phase 1: coalesced stage (64 s-chunks x 512B dense) ----
    const float* mb = m + ((size_t)(b * S_ + s0) * I_ + i0) * C_;
#pragma unroll
    for (int it = 0; it < 8; ++it) {
        int g4  = it * 256 + tid;               // float4 index 0..2047
        int sc  = g4 >> 5;                      // s chunk 0..63
        int rem = g4 & 31;                      // i*8 + c4
        float4 v = *reinterpret_cast<const float4*>(
            mb + (size_t)sc * (I_ * C_) + rem * 4);
        int r = sc * 4 + (rem >> 3);            // row = s*4 + i
        *reinterpret_cast<float4*>(&xs[r * 33 + (rem & 7) * 4]) = v;
    }
    __syncthreads();

    // ---- Phase 2: own-row read (r = tid; banks = (tid+4v)%32, 2-way free) ----
    const float* row = &xs[tid * 33];
    float x[C_];
#pragma unroll
    for (int v = 0; v < 8; ++v) {
        float4 t = reinterpret_cast<const float4*>(row)[v];
        x[4*v+0] = t.x; x[4*v+1] = t.y; x[4*v+2] = t.z; x[4*v+3] = t.w;
    }
    float mu = 0.f;
#pragma unroll
    for (int c = 0; c < C_; ++c) mu += x[c];
    mu *= (1.f / C_);
    float var = 0.f;
#pragma unroll
    for (int c = 0; c < C_; ++c) { float dd = x[c] - mu; var += dd * dd; }
    float rs = rsqrtf(var * (1.f / C_) + EPS_);
#pragma unroll
    for (int c = 0; c < C_; ++c) x[c] = (x[c] - mu) * rs * g[c] + beta[c];

    // ---- pack + swizzled frag-linear mhf write (v11) ----
    char* ldsb = reinterpret_cast<char*>(mhf);
    {
        const int pt   = i_l * 4 + (s_l >> 4);
        const int base = pt * 1024 + (s_l & 15) * 16;
        const int swzb = (i_l & 3) << 5;
#pragma unroll
        for (int ks = 0; ks < 4; ++ks) {
            bf16x8 ch;
#pragma unroll
            for (int e = 0; e < 8; ++e) ch[e] = f2bf(x[ks * 8 + e]);
            *reinterpret_cast<bf16x8*>(ldsb + ((base + ks * 256) ^ swzb)) = ch;
        }
    }
    __syncthreads();   // mhf visible; also: all xs reads done -> trb may overlay

    // ---- A-frag reads (XOR wave-uniform: pt = w*4+q -> pt>>2 = w) ----
    bf16x8 af[4];
#pragma unroll
    for (int q = 0; q < 4; ++q) {
        int pt   = w * 4 + q;
        int byte = (pt * 1024 + lane * 16) ^ ((pt >> 2) << 5);
        af[q] = *reinterpret_cast<const bf16x8*>(ldsb + byte);
    }

    // ---- p-loop: 2 MFMAs live at a time; transpose buf overlays dead xs ----
    __hip_bfloat16* trw = reinterpret_cast<__hip_bfloat16*>(xs) + w * 2304;
    const size_t wbase = (size_t)b * BST + (size_t)sg * SGST
                       + (size_t)ig * IGST + (size_t)w * ILST;
#pragma unroll
    for (int p = 0; p < 2; ++p) {
#pragma unroll
        for (int q = 0; q < 4; ++q) {
#pragma unroll
            for (int fh = 0; fh < 2; ++fh) {
                int f = p * 2 + fh;
                f32x4 d = __builtin_amdgcn_mfma_f32_16x16x32_bf16(
                    af[q], bw[f], (f32x4){0.f, 0.f, 0.f, 0.f}, 0, 0, 0);
                bf16x4 v4;
#pragma unroll
                for (int r = 0; r < 4; ++r) v4[r] = f2bf(d[r] + biasv[f]);
                int c = fh * 16 + lo;
                int s = q * 16 + hi * 4;
                *reinterpret_cast<bf16x4*>(trw + c * 72 + s) = v4;
            }
        }
        __hip_bfloat16* outp = p ? b_t : a_t;
#pragma unroll
        for (int cg = 0; cg < 4; ++cg) {
            int c  = cg * 8 + (lane >> 3);
            int s8 = (lane & 7) * 8;
            bf16x8 vv = *reinterpret_cast<const bf16x8*>(trw + c * 72 + s8);
            // contiguous 1 KiB per wave-store (v11 layout)
            *reinterpret_cast<bf16x8*>(outp + wbase + cg * 512 + lane * 8) = vv;
        }
    }
}

// ---------------------------------------------------------------------------
// Pass 1 (unchanged v11): 64 independent GEMMs, 256x256 tiles, 8 waves,
// BK=32 dbuf via global_load_lds w=16, read-side XOR swizzle with source
// pre-swizzle (rule 21), T1 XCD swizzle, bf16 epilogue with 1/S folded.
// ---------------------------------------------------------------------------
__global__ __launch_bounds__(512, 2) void opm_gemm_kernel(
    const __hip_bfloat16* __restrict__ a_t,
    const __hip_bfloat16* __restrict__ b_t,
    __hip_bfloat16* __restrict__ outer)
{
    __shared__ __align__(16) __hip_bfloat16 sA[2][GBM * BK];  // 16 KiB per buf
    __shared__ __align__(16) __hip_bfloat16 sB[2][GBN * BK];  // total 64 KiB

    const int tid  = threadIdx.x;
    const int wave = tid >> 6;           // 0..7
    const int lane = tid & 63;
    // T1: 256 blocks % 8 == 0 -> bijective chunked swizzle (32 blocks/XCD)
    const int swz  = (blockIdx.x & 7) * 32 + (blockIdx.x >> 3);
    const int bc   = swz >> 2;           // (b*C + c), 0..63
    const int tile = swz & 3;            // 2x2 output tiles per GEMM
    const int i0   = (tile >> 1) * GBM;
    const int j0   = (tile & 1)  * GBN;

    const char* Ap = (const char*)a_t + ((size_t)(bc >> 5) * BST + (size_t)(bc & 31) * 64
                                        + (size_t)(i0 >> 2) * IGST) * 2;
    const char* Bp = (const char*)b_t + ((size_t)(bc >> 5) * BST + (size_t)(bc & 31) * 64
                                        + (size_t)(j0 >> 2) * IGST) * 2;

    f32x4 acc[8][4];
#pragma unroll
    for (int mI = 0; mI < 8; ++mI)
#pragma unroll
        for (int nI = 0; nI < 4; ++nI)
            acc[mI][nI] = (f32x4){0.f, 0.f, 0.f, 0.f};

    const int wr = wave >> 2;      // wave row (0..1): rows [wr*128, +128)
    const int wc = wave & 3;       // wave col (0..3): cols [wc*64, +64)
    const int half = lane >> 4;    // k-group
    const int lrow = lane & 15;

    // staging: thread -> (row = tid>>2, piece = tid&3); source piece
    // pre-swizzled by (row>>1)&3 so the read-side XOR lands linear (rule 21).
    const int row_me = tid >> 2;                       // 0..127
    const int kb_me  = (((tid & 3) ^ ((tid >> 3) & 3)) << 4);
    const size_t rowoff = ((size_t)(row_me >> 2) * IGST + (size_t)(row_me & 3) * ILST) * 2;
    const size_t ROW128 = (size_t)32 * IGST * 2;       // +128 rows in bytes

#define STAGE(bufidx, t) do {                                                              \
        const size_t sgo = (size_t)((t) >> 1) * (SGST * 2);                                \
        const int    sho = ((t) & 1) * 64;                                                 \
        const char* gA0 = Ap + sgo + rowoff + sho + kb_me;                                 \
        const char* gB0 = Bp + sgo + rowoff + sho + kb_me;                                 \
        char* lA = (char*)(&sA[bufidx][0]) + tid * 16;                                     \
        char* lB = (char*)(&sB[bufidx][0]) + tid * 16;                                     \
        __builtin_amdgcn_global_load_lds((const __attribute__((address_space(1))) void*)gA0,              \
                                         (__attribute__((address_space(3))) void*)lA, 16, 0, 0);          \
        __builtin_amdgcn_global_load_lds((const __attribute__((address_space(1))) void*)(gA0 + ROW128),   \
                                         (__attribute__((address_space(3))) void*)(lA + 8192), 16, 0, 0); \
        __builtin_amdgcn_global_load_lds((const __attribute__((address_space(1))) void*)gB0,              \
                                         (__attribute__((address_space(3))) void*)lB, 16, 0, 0);          \
        __builtin_amdgcn_global_load_lds((const __attribute__((address_space(1))) void*)(gB0 + ROW128),   \
                                         (__attribute__((address_space(3))) void*)(lB + 8192), 16, 0, 0); \
    } while (0)

    STAGE(0, 0);
    asm volatile("s_waitcnt vmcnt(0)" ::: "memory");
    __syncthreads();

#pragma unroll 2
    for (int t = 0; t < NT; ++t) {
        const int cur = t & 1;
        if (t + 1 < NT) STAGE(cur ^ 1, t + 1);   // prefetch next K-slab

        const char* lA = (const char*)(&sA[cur][0]);
        const char* lB = (const char*)(&sB[cur][0]);
        bf16x8 af[8], bfr[4];
#pragma unroll
        for (int mI = 0; mI < 8; ++mI) {
            int row  = wr * 128 + mI * 16 + lrow;
            int byte = (row * 64 + half * 16) ^ (((row >> 1) & 3) << 4);
            af[mI] = *reinterpret_cast<const bf16x8*>(lA + byte);
        }
#pragma unroll
        for (int nI = 0; nI < 4; ++nI) {
            int row  = wc * 64 + nI * 16 + lrow;
            int byte = (row * 64 + half * 16) ^ (((row >> 1) & 3) << 4);
            bfr[nI] = *reinterpret_cast<const bf16x8*>(lB + byte);
        }
#pragma unroll
        for (int mI = 0; mI < 8; ++mI)
#pragma unroll
            for (int nI = 0; nI < 4; ++nI)
                acc[mI][nI] = __builtin_amdgcn_mfma_f32_16x16x32_bf16(af[mI], bfr[nI], acc[mI][nI], 0, 0, 0);

        __syncthreads();   // drains vmcnt+lgkmcnt (buffers safe to swap)
    }
#undef STAGE

    // C/D layout: col = lane&15 (from B), row = (lane>>4)*4 + reg (from A)
    __hip_bfloat16* Op = outer + (size_t)bc * (I_ * I_);
#pragma unroll
    for (int mI = 0; mI < 8; ++mI) {
        int ii = i0 + wr * 128 + mI * 16 + half * 4;
#pragma unroll
        for (int nI = 0; nI < 4; ++nI) {
            int jj = j0 + wc * 64 + nI * 16 + lrow;
#pragma unroll
            for (int r = 0; r < 4; ++r)
                Op[(size_t)(ii + r) * I_ + jj] =
                    __float2bfloat16(acc[mI][nI][r] * (1.f / S_));
        }
    }
}

// ---------------------------------------------------------------------------
// Pass 2: out[b,i,j,c] = bo[c] + sum_c' Wo[c,c'] * outer_scaled[(b,c'),i,j]
// ---------------------------------------------------------------------------
__global__ __launch_bounds__(256) void wo_kernel(
    const __hip_bfloat16* __restrict__ outer,
    const float* __restrict__ Wo, const float* __restrict__ bo,
    float* __restrict__ out)
{
    int tid = blockIdx.x * 256 + threadIdx.x;   // ((b*I + i)*J + j)
    int j  = tid & (I_ - 1);
    int bi = tid >> 9;
    int i  = bi & (I_ - 1);
    int b  = bi >> 9;

    const __hip_bfloat16* ip = outer + ((size_t)(b * C_) * I_ + i) * I_ + j;
    float v[C_];
#pragma unroll
    for (int c = 0; c < C_; ++c) v[c] = __bfloat162float(ip[(size_t)c * (I_ * I_)]);

    float o[C_];
#pragma unroll
    for (int c = 0; c < C_; ++c) {
        float acc = bo[c];
#pragma unroll
        for (int k = 0; k < C_; ++k) acc = fmaf(Wo[c * C_ + k], v[k], acc);
        o[c] = acc;
    }

    float* op = out + (size_t)tid * C_;
#pragma unroll
    for (int vv = 0; vv < 8; ++vv) {
        float4 t4 = { o[4*vv+0], o[4*vv+1], o[4*vv+2], o[4*vv+3] };
        reinterpret_cast<float4*>(op)[vv] = t4;
    }
}

// ---------------------------------------------------------------------------
extern "C" void kernel_launch(void* const* d_in, const int* in_sizes, int n_in,
                              void* d_out, int out_size, void* d_ws, size_t ws_size,
                              hipStream_t stream) {
    const float* m    = (const float*)d_in[0];
    const float* ln_g = (const float*)d_in[1];
    const float* ln_b = (const float*)d_in[2];
    const float* Wa   = (const float*)d_in[3];
    const float* ba   = (const float*)d_in[4];
    const float* Wb   = (const float*)d_in[5];
    const float* bb   = (const float*)d_in[6];
    const float* Wo   = (const float*)d_in[7];
    const float* bo   = (const float*)d_in[8];
    float* out = (float*)d_out;

    const size_t AEL = (size_t)B_ * BST;            // elems per array (padded)
    const size_t nO  = (size_t)B_ * C_ * I_ * I_;   // 16,777,216 elems (32 MiB bf16)
    const size_t need = (AEL * 2 + nO) * sizeof(__hip_bfloat16);  // ~169 MB
    if (ws_size < need) return;   // diagnostic: output stays zero -> ws too small

    __hip_bfloat16* a_t = (__hip_bfloat16*)d_ws;
    __hip_bfloat16* b_t = a_t + AEL;
    __hip_bfloat16* outer = b_t + AEL;

    ln_proj_kernel<<<B_ * 16 * 128, 256, 0, stream>>>(m, ln_g, ln_b, Wa, ba, Wb, bb, a_t, b_t);
    opm_gemm_kernel<<<B_ * C_ * 4, 512, 0, stream>>>(a_t, b_t, outer);
    wo_kernel<<<(B_ * I_ * I_) / 256, 256, 0, stream>>>(outer, Wo, bo, out);
}

// Round 15
// 130.672 us; speedup vs baseline: 1.2552x; 1.0794x over previous
//
#include <hip/hip_runtime.h>
#include <hip/hip_bf16.h>

// Problem constants
#define B_ 2
#define S_ 1024
#define I_ 512
#define C_ 32
#define EPS_ 1e-5f

// ---------------------------------------------------------------------------
// a_t/b_t layout (fp8 e4m3, BYTE strides): [b][sg][ig][i_l][c][s64]
//   s64: 64 B contiguous; c: stride 64 B -> wave block 2 KB contiguous
//   i_l: ILST=2064 B (2048 used + 16 pad, non-pow2), ig: 4*ILST,
//   sg: 128*IGST, b: 16*SGST.  Total per array ~33.8 MB.
// ---------------------------------------------------------------------------
#define ILST 2064
#define IGST (4 * ILST)            // 8256 B
#define SGST (128 * IGST)          // 1,056,768 B
#define BST  (16 * SGST)           // 16,908,288 B

// GEMM tiling: 256x256 tile, 8 waves, BK=32, double-buffered.
#define GBM 256
#define GBN 256
#define BK 32
#define NT (S_ / BK)   // 32 K-steps

typedef __attribute__((ext_vector_type(8))) short bf16x8;   // 8 bf16 (MFMA bf16 A/B frag)
typedef __attribute__((ext_vector_type(4))) short bf16x4;
typedef __attribute__((ext_vector_type(4))) float f32x4;    // MFMA C/D frag
typedef __attribute__((ext_vector_type(2))) int  i32x2;     // 8 B

static __device__ __forceinline__ short f2bf(float f) {
    union { __hip_bfloat16 h; short s; } u;
    u.h = __float2bfloat16(f);
    return u.s;
}

// ---------------------------------------------------------------------------
// Pass 0 (v15): v13 structure (coalesced staged reads, per-thread-row LN,
// bf16 MFMA projection), FP8 e4m3 output via v_cvt_pk_fp8_f32.
//
// Round-14 post-mortem: NaN came from the trw transpose path — int-typed
// LDS writes vs long-typed reads with no compiler barrier; TBAA let the
// read hoist above the writes, reading stale f32 staging bytes as fp8
// (0x7F/0xFF = e4m3 NaN). Fix: int/int2 types + asm memory fences around
// the read phase (zero codegen cost; HW DS is in-order within a wave).
// ---------------------------------------------------------------------------
__global__ __launch_bounds__(256) void ln_proj_kernel(
    const float* __restrict__ m,
    const float* __restrict__ g, const float* __restrict__ beta,
    const float* __restrict__ Wa, const float* __restrict__ ba,
    const float* __restrict__ Wb, const float* __restrict__ bb,
    char* __restrict__ a_t, char* __restrict__ b_t)
{
    __shared__ __align__(16) float xs[256 * 33 + 4];        // 33.8 KiB staging
    __shared__ __align__(16) __hip_bfloat16 mhf[8192];      // 16 KiB frag-linear mh

    const int tid  = threadIdx.x;
    const int lane = tid & 63;
    const int w    = tid >> 6;
    const int lo   = lane & 15;
    const int hi   = lane >> 4;

    const int blk = blockIdx.x;                 // ((b*16 + sg)*128 + ig), ig fastest
    const int ig = blk & 127;
    const int sg = (blk >> 7) & 15;
    const int b  = blk >> 11;
    const int s0 = sg * 64;
    const int i0 = ig * 4;

    const int i_l = tid & 3;
    const int s_l = tid >> 2;

    // ---- B-frags: Wa/Wb rows as bf16x8 (lane l: W[c=(f&1)*16+lo][k=hi*8+e]) ----
    bf16x8 bw[4];
    float biasv[4];
#pragma unroll
    for (int f = 0; f < 4; ++f) {
        const float* Wsrc = (f & 2) ? Wb : Wa;
        const float* bsrc = (f & 2) ? bb : ba;
        int c = (f & 1) * 16 + lo;
        const float* src = Wsrc + c * C_ + hi * 8;
        float4 u0 = *reinterpret_cast<const float4*>(src);
        float4 u1 = *reinterpret_cast<const float4*>(src + 4);
        bf16x8 ch;
        ch[0] = f2bf(u0.x); ch[1] = f2bf(u0.y); ch[2] = f2bf(u0.z); ch[3] = f2bf(u0.w);
        ch[4] = f2bf(u1.x); ch[5] = f2bf(u1.y); ch[6] = f2bf(u1.z); ch[7] = f2bf(u1.w);
        bw[f] = ch;
        biasv[f] = bsrc[c];
    }

    // ---- Phase 1: coalesced stage (64 s-chunks x 512B dense) ----
    const float* mb = m + ((size_t)(b * S_ + s0) * I_ + i0) * C_;
#pragma unroll
    for (int it = 0; it < 8; ++it) {
        int g4  = it * 256 + tid;               // float4 index 0..2047
        int sc  = g4 >> 5;                      // s chunk 0..63
        int rem = g4 & 31;                      // i*8 + c4
        float4 v = *reinterpret_cast<const float4*>(
            mb + (size_t)sc * (I_ * C_) + rem * 4);
        int r = sc * 4 + (rem >> 3);            // row = s*4 + i
        *reinterpret_cast<float4*>(&xs[r * 33 + (rem & 7) * 4]) = v;
    }
    __syncthreads();

    // ---- Phase 2: own-row read (r = tid), LN in registers ----
    const float* row = &xs[tid * 33];
    float x[C_];
#pragma unroll
    for (int v = 0; v < 8; ++v) {
        float4 t = reinterpret_cast<const float4*>(row)[v];
        x[4*v+0] = t.x; x[4*v+1] = t.y; x[4*v+2] = t.z; x[4*v+3] = t.w;
    }
    float mu = 0.f;
#pragma unroll
    for (int c = 0; c < C_; ++c) mu += x[c];
    mu *= (1.f / C_);
    float var = 0.f;
#pragma unroll
    for (int c = 0; c < C_; ++c) { float dd = x[c] - mu; var += dd * dd; }
    float rs = rsqrtf(var * (1.f / C_) + EPS_);
#pragma unroll
    for (int c = 0; c < C_; ++c) x[c] = (x[c] - mu) * rs * g[c] + beta[c];

    // ---- pack + swizzled frag-linear mhf write ----
    char* ldsb = reinterpret_cast<char*>(mhf);
    {
        const int pt   = i_l * 4 + (s_l >> 4);
        const int base = pt * 1024 + (s_l & 15) * 16;
        const int swzb = (i_l & 3) << 5;
#pragma unroll
        for (int ks = 0; ks < 4; ++ks) {
            bf16x8 ch;
#pragma unroll
            for (int e = 0; e < 8; ++e) ch[e] = f2bf(x[ks * 8 + e]);
            *reinterpret_cast<bf16x8*>(ldsb + ((base + ks * 256) ^ swzb)) = ch;
        }
    }
    __syncthreads();   // mhf visible; xs reads done -> transpose buf may overlay

    // ---- A-frag reads (XOR wave-uniform: pt = w*4+q -> pt>>2 = w) ----
    bf16x8 af[4];
#pragma unroll
    for (int q = 0; q < 4; ++q) {
        int pt   = w * 4 + q;
        int byte = (pt * 1024 + lane * 16) ^ ((pt >> 2) << 5);
        af[q] = *reinterpret_cast<const bf16x8*>(ldsb + byte);
    }

    // ---- p-loop: bf16 MFMA, bias, FP8 pack, transpose (overlays dead xs),
    //      contiguous 512B wave-stores. Compiler fences order the LDS
    //      write->read and read->next-write phases (HW DS is wave-in-order).
    char* trw = reinterpret_cast<char*>(xs) + w * 2304;   // wave-private 2304 B
    const size_t wbase = (size_t)b * BST + (size_t)sg * SGST
                       + (size_t)ig * IGST + (size_t)w * ILST;
#pragma unroll
    for (int p = 0; p < 2; ++p) {
#pragma unroll
        for (int q = 0; q < 4; ++q) {
#pragma unroll
            for (int fh = 0; fh < 2; ++fh) {
                int f = p * 2 + fh;
                f32x4 d = __builtin_amdgcn_mfma_f32_16x16x32_bf16(
                    af[q], bw[f], (f32x4){0.f, 0.f, 0.f, 0.f}, 0, 0, 0);
                // pack 4 f32 -> 4 fp8 e4m3 in one dword (bytes s..s+3)
                int pk = __builtin_amdgcn_cvt_pk_fp8_f32(d[0] + biasv[f], d[1] + biasv[f], 0, false);
                pk     = __builtin_amdgcn_cvt_pk_fp8_f32(d[2] + biasv[f], d[3] + biasv[f], pk, true);
                int c = fh * 16 + lo;
                int s = q * 16 + hi * 4;
                *reinterpret_cast<int*>(trw + c * 72 + s) = pk;   // 2 lanes/bank: free
            }
        }
        asm volatile("" ::: "memory");   // fence: trw writes before reads
        char* outp = p ? b_t : a_t;
#pragma unroll
        for (int cg = 0; cg < 4; ++cg) {
            int c  = cg * 8 + (lane >> 3);
            int s8 = (lane & 7) * 8;
            i32x2 vv = *reinterpret_cast<const i32x2*>(trw + c * 72 + s8);
            // elem off = cg*512 + c_rel*64 + s8 = cg*512 + lane*8 -> 512B contiguous/instr
            *reinterpret_cast<i32x2*>(outp + wbase + cg * 512 + lane * 8) = vv;
        }
        asm volatile("" ::: "memory");   // fence: reads before p=1 overwrites
    }
}

// ---------------------------------------------------------------------------
// Pass 1 (v15): fp8 GEMM. 64 independent GEMMs, 256x256 tiles, 8 waves,
// BK=32 dbuf. Rows are 32 B -> one gload_lds instr stages a full 8-KB tile
// side (512 thr x 16 B); frag reads are dense 512-B windows -> NO swizzle
// needed. mfma_f32_16x16x32_fp8_fp8 (i64 operands, k = hi*8+e per lane).
// T1 XCD swizzle; epilogue folds 1/S, stores bf16.
// ---------------------------------------------------------------------------
__global__ __launch_bounds__(512, 2) void opm_gemm_kernel(
    const char* __restrict__ a_t,
    const char* __restrict__ b_t,
    __hip_bfloat16* __restrict__ outer)
{
    __shared__ __align__(16) char sA[2][GBM * BK];  // 8 KiB per buf
    __shared__ __align__(16) char sB[2][GBN * BK];  // total 32 KiB

    const int tid  = threadIdx.x;
    const int wave = tid >> 6;           // 0..7
    const int lane = tid & 63;
    // T1: 256 blocks % 8 == 0 -> bijective chunked swizzle (32 blocks/XCD)
    const int swz  = (blockIdx.x & 7) * 32 + (blockIdx.x >> 3);
    const int bc   = swz >> 2;           // (b*C + c), 0..63
    const int tile = swz & 3;            // 2x2 output tiles per GEMM
    const int i0   = (tile >> 1) * GBM;
    const int j0   = (tile & 1)  * GBN;

    const char* Ap = a_t + (size_t)(bc >> 5) * BST + (size_t)(bc & 31) * 64
                         + (size_t)(i0 >> 2) * IGST;
    const char* Bp = b_t + (size_t)(bc >> 5) * BST + (size_t)(bc & 31) * 64
                         + (size_t)(j0 >> 2) * IGST;

    f32x4 acc[8][4];
#pragma unroll
    for (int mI = 0; mI < 8; ++mI)
#pragma unroll
        for (int nI = 0; nI < 4; ++nI)
            acc[mI][nI] = (f32x4){0.f, 0.f, 0.f, 0.f};

    const int wr = wave >> 2;      // wave row (0..1): rows [wr*128, +128)
    const int wc = wave & 3;       // wave col (0..3): cols [wc*64, +64)
    const int half = lane >> 4;    // k-group (k = half*8 + e)
    const int lrow = lane & 15;

    // staging: thread -> (row = tid>>1, 16B-half = tid&1); LDS dest linear
    // tid*16 = row*32 + half16*16  (row-major [row][32B]) -> no swizzle.
    const int row_me = tid >> 1;                       // 0..255
    const size_t rowoff = (size_t)(row_me >> 2) * IGST + (size_t)(row_me & 3) * ILST
                        + (size_t)(tid & 1) * 16;

#define STAGE(bufidx, t) do {                                                              \
        const size_t sgo = (size_t)((t) >> 1) * SGST;                                      \
        const int    sho = ((t) & 1) * 32;                                                 \
        const char* gA0 = Ap + sgo + rowoff + sho;                                         \
        const char* gB0 = Bp + sgo + rowoff + sho;                                         \
        char* lA = (char*)(&sA[bufidx][0]) + tid * 16;                                     \
        char* lB = (char*)(&sB[bufidx][0]) + tid * 16;                                     \
        __builtin_amdgcn_global_load_lds((const __attribute__((address_space(1))) void*)gA0,      \
                                         (__attribute__((address_space(3))) void*)lA, 16, 0, 0);  \
        __builtin_amdgcn_global_load_lds((const __attribute__((address_space(1))) void*)gB0,      \
                                         (__attribute__((address_space(3))) void*)lB, 16, 0, 0);  \
    } while (0)

    STAGE(0, 0);
    asm volatile("s_waitcnt vmcnt(0)" ::: "memory");
    __syncthreads();

#pragma unroll 2
    for (int t = 0; t < NT; ++t) {
        const int cur = t & 1;
        if (t + 1 < NT) STAGE(cur ^ 1, t + 1);   // prefetch next K-slab

        const char* lA = &sA[cur][0];
        const char* lB = &sB[cur][0];
        long aF[8], bF[4];
#pragma unroll
        for (int mI = 0; mI < 8; ++mI) {
            int row = wr * 128 + mI * 16 + lrow;
            aF[mI] = *reinterpret_cast<const long*>(lA + row * 32 + half * 8);
        }
#pragma unroll
        for (int nI = 0; nI < 4; ++nI) {
            int row = wc * 64 + nI * 16 + lrow;
            bF[nI] = *reinterpret_cast<const long*>(lB + row * 32 + half * 8);
        }
#pragma unroll
        for (int mI = 0; mI < 8; ++mI)
#pragma unroll
            for (int nI = 0; nI < 4; ++nI)
                acc[mI][nI] = __builtin_amdgcn_mfma_f32_16x16x32_fp8_fp8(
                    aF[mI], bF[nI], acc[mI][nI], 0, 0, 0);

        __syncthreads();   // drains vmcnt+lgkmcnt (buffers safe to swap)
    }
#undef STAGE

    // C/D layout (dtype-independent): col = lane&15, row = (lane>>4)*4 + reg
    __hip_bfloat16* Op = outer + (size_t)bc * (I_ * I_);
#pragma unroll
    for (int mI = 0; mI < 8; ++mI) {
        int ii = i0 + wr * 128 + mI * 16 + half * 4;
#pragma unroll
        for (int nI = 0; nI < 4; ++nI) {
            int jj = j0 + wc * 64 + nI * 16 + lrow;
#pragma unroll
            for (int r = 0; r < 4; ++r)
                Op[(size_t)(ii + r) * I_ + jj] =
                    __float2bfloat16(acc[mI][nI][r] * (1.f / S_));
        }
    }
}

// ---------------------------------------------------------------------------
// Pass 2: out[b,i,j,c] = bo[c] + sum_c' Wo[c,c'] * outer_scaled[(b,c'),i,j]
// ---------------------------------------------------------------------------
__global__ __launch_bounds__(256) void wo_kernel(
    const __hip_bfloat16* __restrict__ outer,
    const float* __restrict__ Wo, const float* __restrict__ bo,
    float* __restrict__ out)
{
    int tid = blockIdx.x * 256 + threadIdx.x;   // ((b*I + i)*J + j)
    int j  = tid & (I_ - 1);
    int bi = tid >> 9;
    int i  = bi & (I_ - 1);
    int b  = bi >> 9;

    const __hip_bfloat16* ip = outer + ((size_t)(b * C_) * I_ + i) * I_ + j;
    float v[C_];
#pragma unroll
    for (int c = 0; c < C_; ++c) v[c] = __bfloat162float(ip[(size_t)c * (I_ * I_)]);

    float o[C_];
#pragma unroll
    for (int c = 0; c < C_; ++c) {
        float acc = bo[c];
#pragma unroll
        for (int k = 0; k < C_; ++k) acc = fmaf(Wo[c * C_ + k], v[k], acc);
        o[c] = acc;
    }

    float* op = out + (size_t)tid * C_;
#pragma unroll
    for (int vv = 0; vv < 8; ++vv) {
        float4 t4 = { o[4*vv+0], o[4*vv+1], o[4*vv+2], o[4*vv+3] };
        reinterpret_cast<float4*>(op)[vv] = t4;
    }
}

// ---------------------------------------------------------------------------
extern "C" void kernel_launch(void* const* d_in, const int* in_sizes, int n_in,
                              void* d_out, int out_size, void* d_ws, size_t ws_size,
                              hipStream_t stream) {
    const float* m    = (const float*)d_in[0];
    const float* ln_g = (const float*)d_in[1];
    const float* ln_b = (const float*)d_in[2];
    const float* Wa   = (const float*)d_in[3];
    const float* ba   = (const float*)d_in[4];
    const float* Wb   = (const float*)d_in[5];
    const float* bb   = (const float*)d_in[6];
    const float* Wo   = (const float*)d_in[7];
    const float* bo   = (const float*)d_in[8];
    float* out = (float*)d_out;

    const size_t ABYTES = (size_t)B_ * BST;          // fp8 bytes per array (~33.8 MB)
    const size_t nO  = (size_t)B_ * C_ * I_ * I_;    // outer elems (32 MiB bf16)
    const size_t need = ABYTES * 2 + nO * sizeof(__hip_bfloat16);  // ~100 MB
    if (ws_size < need) return;   // diagnostic: output stays zero -> ws too small

    char* a_t = (char*)d_ws;
    char* b_t = a_t + ABYTES;
    __hip_bfloat16* outer = (__hip_bfloat16*)(b_t + ABYTES);

    ln_proj_kernel<<<B_ * 16 * 128, 256, 0, stream>>>(m, ln_g, ln_b, Wa, ba, Wb, bb, a_t, b_t);
    opm_gemm_kernel<<<B_ * C_ * 4, 512, 0, stream>>>(a_t, b_t, outer);
    wo_kernel<<<(B_ * I_ * I_) / 256, 256, 0, stream>>>(outer, Wo, bo, out);
}

// Round 16
// 130.054 us; speedup vs baseline: 1.2611x; 1.0048x over previous
//
#include <hip/hip_runtime.h>
#include <hip/hip_bf16.h>

// Problem constants
#define B_ 2
#define S_ 1024
#define I_ 512
#define C_ 32
#define EPS_ 1e-5f

// ---------------------------------------------------------------------------
// a_t/b_t layout (fp8 e4m3, BYTE strides): [b][sg][ig][i_l][c][s64]
//   s64: 64 B contiguous; c: stride 64 B -> wave block 2 KB contiguous
//   i_l: ILST=2064 B (2048 used + 16 pad, non-pow2), ig: 4*ILST,
//   sg: 128*IGST, b: 16*SGST.  Total per array ~33.8 MB.
// ---------------------------------------------------------------------------
#define ILST 2064
#define IGST (4 * ILST)            // 8256 B
#define SGST (128 * IGST)          // 1,056,768 B
#define BST  (16 * SGST)           // 16,908,288 B

// GEMM tiling: 256x256 tile, 8 waves, BK=32, double-buffered.
#define GBM 256
#define GBN 256
#define BK 32
#define NT (S_ / BK)   // 32 K-steps

typedef __attribute__((ext_vector_type(8))) short bf16x8;   // 8 bf16 (MFMA bf16 A/B frag)
typedef __attribute__((ext_vector_type(4))) short bf16x4;
typedef __attribute__((ext_vector_type(4))) float f32x4;    // MFMA C/D frag
typedef __attribute__((ext_vector_type(2))) int  i32x2;     // 8 B

static __device__ __forceinline__ short f2bf(float f) {
    union { __hip_bfloat16 h; short s; } u;
    u.h = __float2bfloat16(f);
    return u.s;
}
static __device__ __forceinline__ float bf2f(short s) {
    union { float f; unsigned u; } u;
    u.u = ((unsigned)(unsigned short)s) << 16;
    return u.f;
}

// ---------------------------------------------------------------------------
// Pass 0 (v16): SINGLE-BUFFER staging — raw m staged (as bf16) DIRECTLY into
// the swizzled frag-linear mhf layout; LN done in-place (read own row from
// mhf, normalize in regs, write back to same slots). Deletes the xs buffer:
// LDS 50.7 -> 25.6 KB (6 blocks/CU, was 3), one fewer LDS round-trip,
// still 2 barriers, reads stay coalesced (the lever that worked in r13).
// bf16-rounding of m before LN adds ~0.4% rel on mh — negligible vs the
// accepted fp8 3.6% on a/b.
// ---------------------------------------------------------------------------
__global__ __launch_bounds__(256) void ln_proj_kernel(
    const float* __restrict__ m,
    const float* __restrict__ g, const float* __restrict__ beta,
    const float* __restrict__ Wa, const float* __restrict__ ba,
    const float* __restrict__ Wb, const float* __restrict__ bb,
    char* __restrict__ a_t, char* __restrict__ b_t)
{
    __shared__ __align__(16) __hip_bfloat16 mhf[8192];   // 16 KiB frag-linear mh
    __shared__ __align__(16) char trb[4 * 2304];         // 9 KiB fp8 transpose (wave-private)

    const int tid  = threadIdx.x;
    const int lane = tid & 63;
    const int w    = tid >> 6;
    const int lo   = lane & 15;
    const int hi   = lane >> 4;

    const int blk = blockIdx.x;                 // ((b*16 + sg)*128 + ig), ig fastest
    const int ig = blk & 127;
    const int sg = (blk >> 7) & 15;
    const int b  = blk >> 11;
    const int s0 = sg * 64;
    const int i0 = ig * 4;

    const int i_l = tid & 3;
    const int s_l = tid >> 2;

    // ---- B-frags: Wa/Wb rows as bf16x8 (lane l: W[c=(f&1)*16+lo][k=hi*8+e]) ----
    bf16x8 bw[4];
    float biasv[4];
#pragma unroll
    for (int f = 0; f < 4; ++f) {
        const float* Wsrc = (f & 2) ? Wb : Wa;
        const float* bsrc = (f & 2) ? bb : ba;
        int c = (f & 1) * 16 + lo;
        const float* src = Wsrc + c * C_ + hi * 8;
        float4 u0 = *reinterpret_cast<const float4*>(src);
        float4 u1 = *reinterpret_cast<const float4*>(src + 4);
        bf16x8 ch;
        ch[0] = f2bf(u0.x); ch[1] = f2bf(u0.y); ch[2] = f2bf(u0.z); ch[3] = f2bf(u0.w);
        ch[4] = f2bf(u1.x); ch[5] = f2bf(u1.y); ch[6] = f2bf(u1.z); ch[7] = f2bf(u1.w);
        bw[f] = ch;
        biasv[f] = bsrc[c];
    }

    char* ldsb = reinterpret_cast<char*>(mhf);

    // ---- Phase 1: coalesced stage of raw m (bf16) DIRECTLY frag-linear ----
    // lane decomp per it: sc = s-chunk, i_lr = row's i, slot = 4-c group.
    // dest slot: pt = i_lr*4 + (sc>>4); byte = pt*1024 + (slot>>1)*256 +
    // (sc&15)*16 + (slot&1)*8, XOR (i_lr<<5). Banks: 16 pairs x 4 = floor.
    const float* mb = m + ((size_t)(b * S_ + s0) * I_ + i0) * C_;
#pragma unroll
    for (int it = 0; it < 8; ++it) {
        int g4   = it * 256 + tid;              // float4 index 0..2047
        int sc   = g4 >> 5;                     // s chunk 0..63
        int rem  = g4 & 31;                     // i_lr*8 + slot
        int i_lr = rem >> 3;
        int slot = rem & 7;
        float4 v = *reinterpret_cast<const float4*>(
            mb + (size_t)sc * (I_ * C_) + rem * 4);
        bf16x4 pk;
        pk[0] = f2bf(v.x); pk[1] = f2bf(v.y); pk[2] = f2bf(v.z); pk[3] = f2bf(v.w);
        int pt   = i_lr * 4 + (sc >> 4);
        int byte = (pt * 1024 + (slot >> 1) * 256 + (sc & 15) * 16 + (slot & 1) * 8)
                   ^ (i_lr << 5);
        *reinterpret_cast<bf16x4*>(ldsb + byte) = pk;
    }
    __syncthreads();

    // ---- Phase 2: in-place LN — read own row (4x b128), normalize, write back ----
    const int pt2  = i_l * 4 + (s_l >> 4);
    const int base = pt2 * 1024 + (s_l & 15) * 16;
    const int swz2 = (i_l & 3) << 5;
    bf16x8 ch[4];
#pragma unroll
    for (int ks = 0; ks < 4; ++ks)
        ch[ks] = *reinterpret_cast<const bf16x8*>(ldsb + ((base + ks * 256) ^ swz2));

    float x[C_];
#pragma unroll
    for (int ks = 0; ks < 4; ++ks)
#pragma unroll
        for (int e = 0; e < 8; ++e) x[ks * 8 + e] = bf2f(ch[ks][e]);

    float mu = 0.f;
#pragma unroll
    for (int c = 0; c < C_; ++c) mu += x[c];
    mu *= (1.f / C_);
    float var = 0.f;
#pragma unroll
    for (int c = 0; c < C_; ++c) { float dd = x[c] - mu; var += dd * dd; }
    float rs = rsqrtf(var * (1.f / C_) + EPS_);
#pragma unroll
    for (int c = 0; c < C_; ++c) x[c] = (x[c] - mu) * rs * g[c] + beta[c];

#pragma unroll
    for (int ks = 0; ks < 4; ++ks) {
        bf16x8 cw;
#pragma unroll
        for (int e = 0; e < 8; ++e) cw[e] = f2bf(x[ks * 8 + e]);
        *reinterpret_cast<bf16x8*>(ldsb + ((base + ks * 256) ^ swz2)) = cw;
    }
    __syncthreads();   // normalized mhf visible block-wide

    // ---- A-frag reads (XOR wave-uniform: pt = w*4+q -> pt>>2 = w) ----
    bf16x8 af[4];
#pragma unroll
    for (int q = 0; q < 4; ++q) {
        int pt   = w * 4 + q;
        int byte = (pt * 1024 + lane * 16) ^ ((pt >> 2) << 5);
        af[q] = *reinterpret_cast<const bf16x8*>(ldsb + byte);
    }

    // ---- p-loop: bf16 MFMA, bias, FP8 pack, transpose (trb separate),
    //      contiguous 512B wave-stores. Fences order trw write->read phases.
    char* trw = trb + w * 2304;   // wave-private 2304 B
    const size_t wbase = (size_t)b * BST + (size_t)sg * SGST
                       + (size_t)ig * IGST + (size_t)w * ILST;
#pragma unroll
    for (int p = 0; p < 2; ++p) {
#pragma unroll
        for (int q = 0; q < 4; ++q) {
#pragma unroll
            for (int fh = 0; fh < 2; ++fh) {
                int f = p * 2 + fh;
                f32x4 d = __builtin_amdgcn_mfma_f32_16x16x32_bf16(
                    af[q], bw[f], (f32x4){0.f, 0.f, 0.f, 0.f}, 0, 0, 0);
                // pack 4 f32 -> 4 fp8 e4m3 in one dword (bytes s..s+3)
                int pk = __builtin_amdgcn_cvt_pk_fp8_f32(d[0] + biasv[f], d[1] + biasv[f], 0, false);
                pk     = __builtin_amdgcn_cvt_pk_fp8_f32(d[2] + biasv[f], d[3] + biasv[f], pk, true);
                int c = fh * 16 + lo;
                int s = q * 16 + hi * 4;
                *reinterpret_cast<int*>(trw + c * 72 + s) = pk;   // 2 lanes/bank: free
            }
        }
        asm volatile("" ::: "memory");   // fence: trw writes before reads
        char* outp = p ? b_t : a_t;
#pragma unroll
        for (int cg = 0; cg < 4; ++cg) {
            int c  = cg * 8 + (lane >> 3);
            int s8 = (lane & 7) * 8;
            i32x2 vv = *reinterpret_cast<const i32x2*>(trw + c * 72 + s8);
            // elem off = cg*512 + c_rel*64 + s8 = cg*512 + lane*8 -> 512B contiguous/instr
            *reinterpret_cast<i32x2*>(outp + wbase + cg * 512 + lane * 8) = vv;
        }
        asm volatile("" ::: "memory");   // fence: reads before p=1 overwrites
    }
}

// ---------------------------------------------------------------------------
// Pass 1 (unchanged v15): fp8 GEMM. 64 independent GEMMs, 256x256 tiles,
// 8 waves, BK=32 dbuf. Rows are 32 B -> dense 512-B frag windows, no
// swizzle needed. mfma_f32_16x16x32_fp8_fp8. T1 XCD swizzle; epilogue
// folds 1/S, stores bf16.
// ---------------------------------------------------------------------------
__global__ __launch_bounds__(512, 2) void opm_gemm_kernel(
    const char* __restrict__ a_t,
    const char* __restrict__ b_t,
    __hip_bfloat16* __restrict__ outer)
{
    __shared__ __align__(16) char sA[2][GBM * BK];  // 8 KiB per buf
    __shared__ __align__(16) char sB[2][GBN * BK];  // total 32 KiB

    const int tid  = threadIdx.x;
    const int wave = tid >> 6;           // 0..7
    const int lane = tid & 63;
    // T1: 256 blocks % 8 == 0 -> bijective chunked swizzle (32 blocks/XCD)
    const int swz  = (blockIdx.x & 7) * 32 + (blockIdx.x >> 3);
    const int bc   = swz >> 2;           // (b*C + c), 0..63
    const int tile = swz & 3;            // 2x2 output tiles per GEMM
    const int i0   = (tile >> 1) * GBM;
    const int j0   = (tile & 1)  * GBN;

    const char* Ap = a_t + (size_t)(bc >> 5) * BST + (size_t)(bc & 31) * 64
                         + (size_t)(i0 >> 2) * IGST;
    const char* Bp = b_t + (size_t)(bc >> 5) * BST + (size_t)(bc & 31) * 64
                         + (size_t)(j0 >> 2) * IGST;

    f32x4 acc[8][4];
#pragma unroll
    for (int mI = 0; mI < 8; ++mI)
#pragma unroll
        for (int nI = 0; nI < 4; ++nI)
            acc[mI][nI] = (f32x4){0.f, 0.f, 0.f, 0.f};

    const int wr = wave >> 2;      // wave row (0..1): rows [wr*128, +128)
    const int wc = wave & 3;       // wave col (0..3): cols [wc*64, +64)
    const int half = lane >> 4;    // k-group (k = half*8 + e)
    const int lrow = lane & 15;

    // staging: thread -> (row = tid>>1, 16B-half = tid&1); LDS dest linear
    const int row_me = tid >> 1;                       // 0..255
    const size_t rowoff = (size_t)(row_me >> 2) * IGST + (size_t)(row_me & 3) * ILST
                        + (size_t)(tid & 1) * 16;

#define STAGE(bufidx, t) do {                                                              \
        const size_t sgo = (size_t)((t) >> 1) * SGST;                                      \
        const int    sho = ((t) & 1) * 32;                                                 \
        const char* gA0 = Ap + sgo + rowoff + sho;                                         \
        const char* gB0 = Bp + sgo + rowoff + sho;                                         \
        char* lA = (char*)(&sA[bufidx][0]) + tid * 16;                                     \
        char* lB = (char*)(&sB[bufidx][0]) + tid * 16;                                     \
        __builtin_amdgcn_global_load_lds((const __attribute__((address_space(1))) void*)gA0,      \
                                         (__attribute__((address_space(3))) void*)lA, 16, 0, 0);  \
        __builtin_amdgcn_global_load_lds((const __attribute__((address_space(1))) void*)gB0,      \
                                         (__attribute__((address_space(3))) void*)lB, 16, 0, 0);  \
    } while (0)

    STAGE(0, 0);
    asm volatile("s_waitcnt vmcnt(0)" ::: "memory");
    __syncthreads();

#pragma unroll 2
    for (int t = 0; t < NT; ++t) {
        const int cur = t & 1;
        if (t + 1 < NT) STAGE(cur ^ 1, t + 1);   // prefetch next K-slab

        const char* lA = &sA[cur][0];
        const char* lB = &sB[cur][0];
        long aF[8], bF[4];
#pragma unroll
        for (int mI = 0; mI < 8; ++mI) {
            int row = wr * 128 + mI * 16 + lrow;
            aF[mI] = *reinterpret_cast<const long*>(lA + row * 32 + half * 8);
        }
#pragma unroll
        for (int nI = 0; nI < 4; ++nI) {
            int row = wc * 64 + nI * 16 + lrow;
            bF[nI] = *reinterpret_cast<const long*>(lB + row * 32 + half * 8);
        }
#pragma unroll
        for (int mI = 0; mI < 8; ++mI)
#pragma unroll
            for (int nI = 0; nI < 4; ++nI)
                acc[mI][nI] = __builtin_amdgcn_mfma_f32_16x16x32_fp8_fp8(
                    aF[mI], bF[nI], acc[mI][nI], 0, 0, 0);

        __syncthreads();   // drains vmcnt+lgkmcnt (buffers safe to swap)
    }
#undef STAGE

    // C/D layout (dtype-independent): col = lane&15, row = (lane>>4)*4 + reg
    __hip_bfloat16* Op = outer + (size_t)bc * (I_ * I_);
#pragma unroll
    for (int mI = 0; mI < 8; ++mI) {
        int ii = i0 + wr * 128 + mI * 16 + half * 4;
#pragma unroll
        for (int nI = 0; nI < 4; ++nI) {
            int jj = j0 + wc * 64 + nI * 16 + lrow;
#pragma unroll
            for (int r = 0; r < 4; ++r)
                Op[(size_t)(ii + r) * I_ + jj] =
                    __float2bfloat16(acc[mI][nI][r] * (1.f / S_));
        }
    }
}

// ---------------------------------------------------------------------------
// Pass 2: out[b,i,j,c] = bo[c] + sum_c' Wo[c,c'] * outer_scaled[(b,c'),i,j]
// ---------------------------------------------------------------------------
__global__ __launch_bounds__(256) void wo_kernel(
    const __hip_bfloat16* __restrict__ outer,
    const float* __restrict__ Wo, const float* __restrict__ bo,
    float* __restrict__ out)
{
    int tid = blockIdx.x * 256 + threadIdx.x;   // ((b*I + i)*J + j)
    int j  = tid & (I_ - 1);
    int bi = tid >> 9;
    int i  = bi & (I_ - 1);
    int b  = bi >> 9;

    const __hip_bfloat16* ip = outer + ((size_t)(b * C_) * I_ + i) * I_ + j;
    float v[C_];
#pragma unroll
    for (int c = 0; c < C_; ++c) v[c] = __bfloat162float(ip[(size_t)c * (I_ * I_)]);

    float o[C_];
#pragma unroll
    for (int c = 0; c < C_; ++c) {
        float acc = bo[c];
#pragma unroll
        for (int k = 0; k < C_; ++k) acc = fmaf(Wo[c * C_ + k], v[k], acc);
        o[c] = acc;
    }

    float* op = out + (size_t)tid * C_;
#pragma unroll
    for (int vv = 0; vv < 8; ++vv) {
        float4 t4 = { o[4*vv+0], o[4*vv+1], o[4*vv+2], o[4*vv+3] };
        reinterpret_cast<float4*>(op)[vv] = t4;
    }
}

// ---------------------------------------------------------------------------
extern "C" void kernel_launch(void* const* d_in, const int* in_sizes, int n_in,
                              void* d_out, int out_size, void* d_ws, size_t ws_size,
                              hipStream_t stream) {
    const float* m    = (const float*)d_in[0];
    const float* ln_g = (const float*)d_in[1];
    const float* ln_b = (const float*)d_in[2];
    const float* Wa   = (const float*)d_in[3];
    const float* ba   = (const float*)d_in[4];
    const float* Wb   = (const float*)d_in[5];
    const float* bb   = (const float*)d_in[6];
    const float* Wo   = (const float*)d_in[7];
    const float* bo   = (const float*)d_in[8];
    float* out = (float*)d_out;

    const size_t ABYTES = (size_t)B_ * BST;          // fp8 bytes per array (~33.8 MB)
    const size_t nO  = (size_t)B_ * C_ * I_ * I_;    // outer elems (32 MiB bf16)
    const size_t need = ABYTES * 2 + nO * sizeof(__hip_bfloat16);  // ~100 MB
    if (ws_size < need) return;   // diagnostic: output stays zero -> ws too small

    char* a_t = (char*)d_ws;
    char* b_t = a_t + ABYTES;
    __hip_bfloat16* outer = (__hip_bfloat16*)(b_t + ABYTES);

    ln_proj_kernel<<<B_ * 16 * 128, 256, 0, stream>>>(m, ln_g, ln_b, Wa, ba, Wb, bb, a_t, b_t);
    opm_gemm_kernel<<<B_ * C_ * 4, 512, 0, stream>>>(a_t, b_t, outer);
    wo_kernel<<<(B_ * I_ * I_) / 256, 256, 0, stream>>>(outer, Wo, bo, out);
}